// Round 1
// baseline (2121.129 us; speedup 1.0000x reference)
//
#include <hip/hip_runtime.h>
#include <cstdint>
#include <cstddef>

// Problem constants (from reference): B=8, C=64, T=250, F=161, H=64, Hh=32, BB=128
#define BBN 128
#define NBT 2000          // B*T groups
#define NF  161
#define NH  64
#define ROW 64            // channels per row
#define GROUP (NF * NH)   // 10304 elements per LN group
#define ELEMS 20608000    // 2000*161*64

// ---------- helpers ----------
__device__ __forceinline__ uint32_t bf16_rne(float f) {
  uint32_t u = __float_as_uint(f);
  return (u + 0x7fffu + ((u >> 16) & 1u)) >> 16;  // round-to-nearest-even bf16
}
__device__ __forceinline__ uint32_t pack2bf(float lo, float hi) {
  return bf16_rne(lo) | (bf16_rne(hi) << 16);
}
__device__ __forceinline__ float bflo(uint32_t w) { return __uint_as_float(w << 16); }
__device__ __forceinline__ float bfhi(uint32_t w) { return __uint_as_float(w & 0xffff0000u); }

__device__ __forceinline__ float lecun_tanh_f(float x) {
  // 1.7159 * tanh(0.666 x) ; tanh(y) = 1 - 2/(e^{2y}+1); safe at +-inf
  float e = __expf(1.332f * x);
  return 1.7159f * (1.f - __fdividef(2.f, e + 1.f));
}

// Wave-local LDS fence: buffers in the scan kernel are wave-private, so a
// full __syncthreads() is unnecessary; we only need this wave's LDS ops
// retired before dependent cross-lane reads (rule #18: sched_barrier after).
__device__ __forceinline__ void wave_fence() {
  asm volatile("s_waitcnt lgkmcnt(0)" ::: "memory");
  __builtin_amdgcn_sched_barrier(0);
}

// ---------- K0: x (B,C,T,F) -> xp (B*T, F, C) ----------
__global__ __launch_bounds__(256) void transpose_kernel(
    const float* __restrict__ x, float* __restrict__ xp) {
  __shared__ float tile[32][33];
  const int bt = blockIdx.x;                 // b*250 + t
  const int b = bt / 250, t = bt - b * 250;
  const int f0 = blockIdx.y * 32;
  const int c0 = blockIdx.z * 32;
  const int tx = threadIdx.x & 31;
  const int ty4 = (threadIdx.x >> 5) * 4;
  const int f_in = f0 + tx;
#pragma unroll
  for (int i = 0; i < 4; ++i) {
    int c = c0 + ty4 + i;
    if (f_in < NF)
      tile[ty4 + i][tx] = x[((size_t)(b * 64 + c) * 250 + t) * NF + f_in];
  }
  __syncthreads();
  const int c_out = c0 + tx;
#pragma unroll
  for (int i = 0; i < 4; ++i) {
    int f = f0 + ty4 + i;
    if (f < NF)
      xp[((size_t)bt * NF + f) * 64 + c_out] = tile[tx][ty4 + i];
  }
}

// ---------- K1/K3: CfC scan ----------
// One wave owns S sequences end-to-end (no inter-wave deps -> no block
// barriers in the step loop). Weights bf16-packed in LDS (halves LDS BW),
// all state/accumulation fp32.
// Blocks [0,blocksPerDir) -> weights0, forward; [blocksPerDir,2x) -> weights1,
// reversed input order, output column offset o_col_per_dir (faithful to the
// reference: reverse branch is NOT flipped back).
template <int HD, int S>
__global__ __launch_bounds__(256) void cfc_scan_kernel(
    const float* __restrict__ in, float* __restrict__ out,
    const float* __restrict__ Wb0, const float* __restrict__ bb0,
    const float* __restrict__ W10, const float* __restrict__ b10,
    const float* __restrict__ wt0, const float* __restrict__ A0,
    const float* __restrict__ Wb1, const float* __restrict__ bb1,
    const float* __restrict__ W11, const float* __restrict__ b11,
    const float* __restrict__ wt1, const float* __restrict__ A1,
    int seq_len, int blocksPerDir, int seqs_per_outer,
    int outer_stride, int inner_stride, int step_stride, int o_col_per_dir) {
  constexpr int ZD = 64 + HD;                 // z = [x(64), h(HD)]
  __shared__ uint32_t WbP[ZD][64];            // packed col-pairs (2j, 2j+1)
  __shared__ uint32_t W1P[64][HD];            // packed k-pairs (2kk, 2kk+1)
  __shared__ float zbuf[4][S][ZD];
  __shared__ float gbuf[4][S][BBN];

  const int dir = (blockIdx.x >= (unsigned)blocksPerDir) ? 1 : 0;
  const int bid = blockIdx.x - dir * blocksPerDir;
  const float* Wb = dir ? Wb1 : Wb0;
  const float* bb = dir ? bb1 : bb0;
  const float* W1 = dir ? W11 : W10;
  const float* b1 = dir ? b11 : b10;
  const float* wt = dir ? wt1 : wt0;
  const float* Aa = dir ? A1 : A0;
  const bool rev = (dir == 1);
  const int tid = threadIdx.x;

  for (int e = tid; e < ZD * 64; e += 256) {
    int k = e >> 6, j = e & 63;
    WbP[k][j] = pack2bf(Wb[k * BBN + 2 * j], Wb[k * BBN + 2 * j + 1]);
  }
  for (int e = tid; e < 64 * HD; e += 256) {
    int kk = e / HD, i = e % HD;
    W1P[kk][i] = pack2bf(W1[(2 * kk) * HD + i], W1[(2 * kk + 1) * HD + i]);
  }
  __syncthreads();

  const int wave = tid >> 6, lane = tid & 63;
  const float bbv0 = bb[2 * lane], bbv1 = bb[2 * lane + 1];
  const int icol = lane & (HD - 1);
  const float b1v = b1[icol];
  const float wtv = fabsf(wt[icol]);
  const float Avv = Aa[icol];

  int ibase[S], obase[S];
#pragma unroll
  for (int s = 0; s < S; ++s) {
    int m = (bid * 4 + wave) * S + s;         // grid sized exactly, no guard
    int ob = m / seqs_per_outer, oi = m - ob * seqs_per_outer;
    ibase[s] = ob * outer_stride + oi * inner_stride;
    obase[s] = ibase[s] + dir * o_col_per_dir;
  }
  if (lane < HD) {
#pragma unroll
    for (int s = 0; s < S; ++s) zbuf[wave][s][64 + lane] = 0.f;  // h0 = 0
  }

  float xreg[S];
  {
    int src0 = rev ? (seq_len - 1) : 0;
#pragma unroll
    for (int s = 0; s < S; ++s)
      xreg[s] = in[ibase[s] + src0 * step_stride + lane];
  }

  for (int st = 0; st < seq_len; ++st) {
    wave_fence();  // prior reads of zbuf done before overwrite (WAR)
#pragma unroll
    for (int s = 0; s < S; ++s) zbuf[wave][s][lane] = xreg[s];
    wave_fence();  // x-writes + last step's h-writes visible to whole wave
    if (st + 1 < seq_len) {
      int srcn = rev ? (seq_len - 2 - st) : (st + 1);
#pragma unroll
      for (int s = 0; s < S; ++s)
        xreg[s] = in[ibase[s] + srcn * step_stride + lane];  // prefetch next x
    }
    // g = lecun_tanh(z @ Wb + bb): lane owns cols (2*lane, 2*lane+1)
    float a0[S], a1[S];
#pragma unroll
    for (int s = 0; s < S; ++s) { a0[s] = bbv0; a1[s] = bbv1; }
#pragma unroll 4
    for (int k2 = 0; k2 < ZD / 2; ++k2) {
      uint32_t wA = WbP[2 * k2][lane];
      uint32_t wB = WbP[2 * k2 + 1][lane];
      float fA0 = bflo(wA), fA1 = bfhi(wA);
      float fB0 = bflo(wB), fB1 = bfhi(wB);
#pragma unroll
      for (int s = 0; s < S; ++s) {
        float2 z2 = *(const float2*)&zbuf[wave][s][2 * k2];
        a0[s] = fmaf(z2.x, fA0, a0[s]);
        a1[s] = fmaf(z2.x, fA1, a1[s]);
        a0[s] = fmaf(z2.y, fB0, a0[s]);
        a1[s] = fmaf(z2.y, fB1, a1[s]);
      }
    }
#pragma unroll
    for (int s = 0; s < S; ++s) {
      float g0 = lecun_tanh_f(a0[s]);
      float g1 = lecun_tanh_f(a1[s]);
      ((float2*)&gbuf[wave][s][0])[lane] = make_float2(g0, g1);
    }
    wave_fence();  // g visible to whole wave
    // ff1 = g @ W1 + b1
    float fa[S];
#pragma unroll
    for (int s = 0; s < S; ++s) fa[s] = 0.f;
    if constexpr (HD == 32) {
      const int kof = (lane >> 5) * 32;  // lane halves split K
#pragma unroll 4
      for (int kk = 0; kk < 32; ++kk) {
        int kx = kof + kk;
        uint32_t w = W1P[kx][icol];
        float f0 = bflo(w), f1 = bfhi(w);
#pragma unroll
        for (int s = 0; s < S; ++s) {
          float2 g2v = ((const float2*)&gbuf[wave][s][0])[kx];
          fa[s] = fmaf(g2v.x, f0, fa[s]);
          fa[s] = fmaf(g2v.y, f1, fa[s]);
        }
      }
#pragma unroll
      for (int s = 0; s < S; ++s) fa[s] += __shfl_xor(fa[s], 32);
    } else {
#pragma unroll 4
      for (int kk = 0; kk < 64; ++kk) {
        uint32_t w = W1P[kk][lane];
        float f0 = bflo(w), f1 = bfhi(w);
#pragma unroll
        for (int s = 0; s < S; ++s) {
          float2 g2v = ((const float2*)&gbuf[wave][s][0])[kk];
          fa[s] = fmaf(g2v.x, f0, fa[s]);
          fa[s] = fmaf(g2v.y, f1, fa[s]);
        }
      }
    }
    // h_new = -A * exp(-(|wtau|+|ff1|)) * ff1 + A
#pragma unroll
    for (int s = 0; s < S; ++s) {
      float ff = fa[s] + b1v;
      float e = __expf(-(wtv + fabsf(ff)));
      float hn = fmaf(-Avv * e, ff, Avv);
      if (lane < HD) {
        zbuf[wave][s][64 + icol] = hn;
        out[obase[s] + st * step_stride + icol] = hn;
      }
    }
  }
}

// ---------- K2/K4: row FC (64x64) + LayerNorm over (F,H) + residual ----------
// One block per (b,t) group. TRANS=false: write (B,T,F,H). TRANS=true:
// write final output transposed to (B,H,T,F).
template <bool TRANS>
__global__ __launch_bounds__(256) void fc_ln_res_kernel(
    const float* __restrict__ yin,    // (2000,161,64)
    const float* __restrict__ resid,  // (2000,161,64)
    const float* __restrict__ W,      // (64,64) [k][h]
    const float* __restrict__ bias,   // (64)
    const float* __restrict__ lng,    // (161,64)
    const float* __restrict__ lnb,    // (161,64)
    float* __restrict__ outp) {
  __shared__ float WshT[64][68];      // transposed, padded (row = 272B, 16B-mult)
  __shared__ float fcbuf[NF * 65];    // padded for transposed read in TRANS path
  __shared__ float ysh[4][64];
  __shared__ float red[16];
  const int tid = threadIdx.x, n = blockIdx.x;
  for (int e = tid; e < 4096; e += 256) WshT[e & 63][e >> 6] = W[e];
  __syncthreads();
  const int h = tid & 63, rl = tid >> 6;
  const float* yrow = yin + (size_t)n * GROUP;
  const float bv = bias[h];
  float sum = 0.f, ssq = 0.f;
  for (int r0 = 0; r0 < NF; r0 += 4) {
    int f = r0 + rl;
    __syncthreads();  // protect ysh reuse
    ysh[rl][h] = (f < NF) ? yrow[f * 64 + h] : 0.f;
    __syncthreads();
    if (f < NF) {
      float acc = bv;
#pragma unroll
      for (int k4 = 0; k4 < 64; k4 += 4) {
        float4 wv = *(const float4*)&WshT[h][k4];
        float4 yv = *(const float4*)&ysh[rl][k4];
        acc = fmaf(yv.x, wv.x, acc);
        acc = fmaf(yv.y, wv.y, acc);
        acc = fmaf(yv.z, wv.z, acc);
        acc = fmaf(yv.w, wv.w, acc);
      }
      fcbuf[f * 65 + h] = acc;
      sum += acc;
      ssq += acc * acc;
    }
  }
#pragma unroll
  for (int off = 32; off; off >>= 1) {
    sum += __shfl_xor(sum, off);
    ssq += __shfl_xor(ssq, off);
  }
  const int wave = tid >> 6, lane = tid & 63;
  if (lane == 0) { red[wave] = sum; red[4 + wave] = ssq; }
  __syncthreads();
  if (tid == 0) {
    float s = red[0] + red[1] + red[2] + red[3];
    float q = red[4] + red[5] + red[6] + red[7];
    float mu = s * (1.f / (float)GROUP);
    float var = q * (1.f / (float)GROUP) - mu * mu;
    var = fmaxf(var, 0.f);
    red[8] = mu;
    red[9] = rsqrtf(var + 1e-8f);
  }
  __syncthreads();
  const float mu = red[8], rstd = red[9];
  const float* rrow = resid + (size_t)n * GROUP;
  if (!TRANS) {
    float* orow = outp + (size_t)n * GROUP;
    for (int e = tid; e < GROUP; e += 256) {
      int f = e >> 6, hh = e & 63;
      orow[e] = (fcbuf[f * 65 + hh] - mu) * rstd * lng[e] + lnb[e] + rrow[e];
    }
  } else {
    for (int e = tid; e < GROUP; e += 256) {
      int f = e >> 6, hh = e & 63;
      fcbuf[f * 65 + hh] =
          (fcbuf[f * 65 + hh] - mu) * rstd * lng[e] + lnb[e] + rrow[e];
    }
    __syncthreads();
    const int b = n / 250, t = n - b * 250;
    float* obase = outp + ((size_t)b * 64 * 250 + t) * NF;  // out[b][h][t][f]
    for (int e = tid; e < GROUP; e += 256) {
      unsigned hh = (unsigned)e / 161u, f = (unsigned)e - hh * 161u;
      obase[(size_t)hh * 250 * NF + f] = fcbuf[f * 65 + hh];
    }
  }
}

// ---------- launcher ----------
extern "C" void kernel_launch(void* const* d_in, const int* in_sizes, int n_in,
                              void* d_out, int out_size, void* d_ws,
                              size_t ws_size, hipStream_t stream) {
  const float* x     = (const float*)d_in[0];
  const float* i1_Wb = (const float*)d_in[1];
  const float* i1_bb = (const float*)d_in[2];
  const float* i1_W1 = (const float*)d_in[3];
  const float* i1_b1 = (const float*)d_in[4];
  const float* i1_wt = (const float*)d_in[5];
  const float* i1_A  = (const float*)d_in[6];
  const float* i2_Wb = (const float*)d_in[7];
  const float* i2_bb = (const float*)d_in[8];
  const float* i2_W1 = (const float*)d_in[9];
  const float* i2_b1 = (const float*)d_in[10];
  const float* i2_wt = (const float*)d_in[11];
  const float* i2_A  = (const float*)d_in[12];
  const float* r_Wb  = (const float*)d_in[13];
  const float* r_bb  = (const float*)d_in[14];
  const float* r_W1  = (const float*)d_in[15];
  const float* r_b1  = (const float*)d_in[16];
  const float* r_wt  = (const float*)d_in[17];
  const float* r_A   = (const float*)d_in[18];
  const float* fcW_i = (const float*)d_in[19];
  const float* fcb_i = (const float*)d_in[20];
  const float* lng_i = (const float*)d_in[21];
  const float* lnb_i = (const float*)d_in[22];
  const float* fcW_r = (const float*)d_in[23];
  const float* fcb_r = (const float*)d_in[24];
  const float* lng_r = (const float*)d_in[25];
  const float* lnb_r = (const float*)d_in[26];

  float* xp        = (float*)d_ws;          // (2000,161,64)
  float* intra_out = xp + ELEMS;            // (2000,161,64)
  float* ybuf      = (float*)d_out;         // intra scan result, dead after K2
  float* inter_y   = xp;                    // reuse xp region (dead after K2)

  // K0: x -> xp
  transpose_kernel<<<dim3(NBT, 6, 2), 256, 0, stream>>>(x, xp);

  // K1: intra bidirectional scans over F. 2000 seqs/dir, 4 waves x S=4 ->
  // 125 blocks per dir, exact.
  cfc_scan_kernel<32, 4><<<250, 256, 0, stream>>>(
      xp, ybuf, i1_Wb, i1_bb, i1_W1, i1_b1, i1_wt, i1_A, i2_Wb, i2_bb, i2_W1,
      i2_b1, i2_wt, i2_A, 161, 125, 2000, 0, GROUP, 64, 32);

  // K2: intra FC + LN(F,H) + residual(xp) -> intra_out
  fc_ln_res_kernel<false><<<NBT, 256, 0, stream>>>(ybuf, xp, fcW_i, fcb_i,
                                                   lng_i, lnb_i, intra_out);

  // K3: inter scan over T. 1288 seqs = 322 blocks x 4 waves x S=1, exact.
  cfc_scan_kernel<64, 1><<<322, 256, 0, stream>>>(
      intra_out, inter_y, r_Wb, r_bb, r_W1, r_b1, r_wt, r_A, r_Wb, r_bb, r_W1,
      r_b1, r_wt, r_A, 250, 322, 161, 250 * NF * 64, 64, GROUP, 0);

  // K4: inter FC + LN + residual(intra_out) + transpose -> d_out (B,H,T,F)
  fc_ln_res_kernel<true><<<NBT, 256, 0, stream>>>(inter_y, intra_out, fcW_r,
                                                  fcb_r, lng_r, lnb_r,
                                                  (float*)d_out);
}

// Round 2
// 1635.409 us; speedup vs baseline: 1.2970x; 1.2970x over previous
//
#include <hip/hip_runtime.h>
#include <cstdint>
#include <cstddef>

// B=8, C=64, T=250, F=161, H=64, Hh=32, BB=128
#define BBN 128
#define NBT 2000
#define NF  161
#define GROUP (NF * 64)       // 10304
#define ELEMS 20608000

typedef __attribute__((ext_vector_type(4))) float f32x4;
typedef __attribute__((ext_vector_type(8))) __bf16 bf16x8;
typedef __attribute__((ext_vector_type(8))) uint16_t u16x8;

__device__ __forceinline__ uint16_t bf16_rne_u16(float f) {
  uint32_t u = __float_as_uint(f);
  return (uint16_t)((u + 0x7fffu + ((u >> 16) & 1u)) >> 16);
}
__device__ __forceinline__ float bf16u_to_f(uint16_t h) {
  return __uint_as_float((uint32_t)h << 16);
}
__device__ __forceinline__ float lecun_tanh_f(float x) {
  float e = __expf(1.332f * x);
  return 1.7159f * (1.f - __fdividef(2.f, e + 1.f));
}
// wave-local LDS fence (blocks are single-wave; rule #18: sched_barrier after)
__device__ __forceinline__ void wave_fence() {
  asm volatile("s_waitcnt lgkmcnt(0)" ::: "memory");
  __builtin_amdgcn_sched_barrier(0);
}
__device__ __forceinline__ f32x4 mfma16(bf16x8 a, bf16x8 b, f32x4 c) {
  return __builtin_amdgcn_mfma_f32_16x16x32_bf16(a, b, c, 0, 0, 0);
}
// build a bf16x8 B-fragment from strided f32 weights
__device__ __forceinline__ bf16x8 pack_frag(const float* __restrict__ base, int stride) {
  u16x8 t;
#pragma unroll
  for (int i = 0; i < 8; ++i) t[i] = bf16_rne_u16(base[i * stride]);
  return __builtin_bit_cast(bf16x8, t);
}

// ---------- K0: x (B,C,T,F) -> xp (B*T,F,C) as f32 AND bf16 ----------
__global__ __launch_bounds__(256) void transpose_kernel(
    const float* __restrict__ x, float* __restrict__ xp,
    uint16_t* __restrict__ xph) {
  __shared__ float tile[32][33];
  const int bt = blockIdx.x;
  const int b = bt / 250, t = bt - b * 250;
  const int f0 = blockIdx.y * 32;
  const int c0 = blockIdx.z * 32;
  const int tx = threadIdx.x & 31;
  const int ty4 = (threadIdx.x >> 5) * 4;
  const int f_in = f0 + tx;
#pragma unroll
  for (int i = 0; i < 4; ++i) {
    int c = c0 + ty4 + i;
    if (f_in < NF)
      tile[ty4 + i][tx] = x[((size_t)(b * 64 + c) * 250 + t) * NF + f_in];
  }
  __syncthreads();
  const int c_out = c0 + tx;
#pragma unroll
  for (int i = 0; i < 4; ++i) {
    int f = f0 + ty4 + i;
    if (f < NF) {
      float v = tile[tx][ty4 + i];
      size_t o = ((size_t)bt * NF + f) * 64 + c_out;
      xp[o] = v;
      xph[o] = bf16_rne_u16(v);
    }
  }
}

// ---------- K1/K3: MFMA CfC scan, 16 sequences per 64-thread block ----------
// A-frag: row=lane&15, k=(lane>>4)*8+i.  B-frag: col=lane&15, k=(lane>>4)*8+i.
// C/D: col=lane&15, row=(lane>>4)*4+reg (m89-verified).
// Backbone: z=[x(64),h(HD)] @ Wb (ZDxBBN) via 16x16x32 MFMA; x-part weight
// frags staged in LDS (step-invariant), h-part + W1 frags in registers.
// g and h cross C-layout -> A-layout through small padded LDS tiles.
template <int HD>
__global__ __launch_bounds__(64) void mfma_scan_kernel(
    const uint16_t* __restrict__ in, uint16_t* __restrict__ out,
    const float* __restrict__ Wb0, const float* __restrict__ bb0,
    const float* __restrict__ W10, const float* __restrict__ b10,
    const float* __restrict__ wt0, const float* __restrict__ A0,
    const float* __restrict__ Wb1, const float* __restrict__ bb1,
    const float* __restrict__ W11, const float* __restrict__ b11,
    const float* __restrict__ wt1, const float* __restrict__ A1,
    int seq_len, int blocksPerDir, int nseq, int seqs_per_outer,
    int outer_stride, int inner_stride, int step_stride,
    int o_seq_stride, int o_step_stride, int o_col_per_dir) {
  constexpr int NKH = HD / 32;   // h ktiles
  constexpr int NM = HD / 16;    // ff1 n-tiles
  __shared__ uint16_t zh[16][HD + 8];    // h state, row-padded (2-way banks)
  __shared__ uint16_t gsh[16][BBN + 8];  // g activations
  __shared__ bf16x8 WbX[16][64];         // x-part Wb frags [kt*8+n][lane]

  const int dir = (blockIdx.x >= (unsigned)blocksPerDir) ? 1 : 0;
  const int bid = blockIdx.x - dir * blocksPerDir;
  const float* __restrict__ Wb = dir ? Wb1 : Wb0;
  const float* __restrict__ bb = dir ? bb1 : bb0;
  const float* __restrict__ W1 = dir ? W11 : W10;
  const float* __restrict__ b1 = dir ? b11 : b10;
  const float* __restrict__ wt = dir ? wt1 : wt0;
  const float* __restrict__ Aa = dir ? A1 : A0;
  const int l = threadIdx.x, l4 = l >> 4, lm = l & 15;

  // ---- one-time weight packing (each element read exactly once) ----
#pragma unroll
  for (int kt = 0; kt < 2; ++kt)
#pragma unroll
    for (int n = 0; n < 8; ++n)
      WbX[kt * 8 + n][l] =
          pack_frag(&Wb[(kt * 32 + l4 * 8) * BBN + 16 * n + lm], BBN);
  bf16x8 WbH[NKH][8];
#pragma unroll
  for (int kt = 0; kt < NKH; ++kt)
#pragma unroll
    for (int n = 0; n < 8; ++n)
      WbH[kt][n] =
          pack_frag(&Wb[(64 + kt * 32 + l4 * 8) * BBN + 16 * n + lm], BBN);
  bf16x8 W1f[4][NM];
#pragma unroll
  for (int kt = 0; kt < 4; ++kt)
#pragma unroll
    for (int m = 0; m < NM; ++m)
      W1f[kt][m] = pack_frag(&W1[(kt * 32 + l4 * 8) * HD + 16 * m + lm], HD);

  float bbv[8];
#pragma unroll
  for (int n = 0; n < 8; ++n) bbv[n] = bb[16 * n + lm];
  float b1v[NM], wtv[NM], Avv[NM];
#pragma unroll
  for (int m = 0; m < NM; ++m) {
    b1v[m] = b1[16 * m + lm];
    wtv[m] = fabsf(wt[16 * m + lm]);
    Avv[m] = Aa[16 * m + lm];
  }

  for (int e = l; e < 16 * (HD + 8); e += 64) ((uint16_t*)zh)[e] = 0;  // h0=0

  // input base: lane's A-frag sequence = lm (clamped for the K3 tail wave)
  int sA = bid * 16 + lm;
  if (sA > nseq - 1) sA = nseq - 1;
  int ob = sA / seqs_per_outer, oi = sA - ob * seqs_per_outer;
  const uint16_t* inp = in + ob * outer_stride + oi * inner_stride + l4 * 8;
  // output bases: C-layout sequence = bid*16 + l4*4 + r
  int obase[4];
  bool omask[4];
#pragma unroll
  for (int r = 0; r < 4; ++r) {
    int s = bid * 16 + l4 * 4 + r;
    omask[r] = (s < nseq);
    if (s > nseq - 1) s = nseq - 1;
    obase[r] = s * o_seq_stride + dir * o_col_per_dir + lm;
  }
  const bool rev = (dir == 1);

  bf16x8 xa, xb;
  {
    int f0 = rev ? (seq_len - 1) : 0;
    xa = *(const bf16x8*)(inp + f0 * step_stride);
    xb = *(const bf16x8*)(inp + f0 * step_stride + 32);
  }

  for (int st = 0; st < seq_len; ++st) {
    wave_fence();  // zh writes (prev step / init) visible wave-wide
    bf16x8 hf[NKH];
#pragma unroll
    for (int kt = 0; kt < NKH; ++kt)
      hf[kt] = *(const bf16x8*)&zh[lm][kt * 32 + l4 * 8];
    bf16x8 nxa = xa, nxb = xb;
    if (st + 1 < seq_len) {  // prefetch next x A-frags (hide HBM latency)
      int f = rev ? (seq_len - 2 - st) : (st + 1);
      nxa = *(const bf16x8*)(inp + f * step_stride);
      nxb = *(const bf16x8*)(inp + f * step_stride + 32);
    }
    // backbone: acc(16 seq x 16 cols) = bb + z @ Wb, then lecun_tanh -> gsh
#pragma unroll
    for (int n = 0; n < 8; ++n) {
      f32x4 acc = {bbv[n], bbv[n], bbv[n], bbv[n]};
      acc = mfma16(xa, WbX[n][l], acc);
      acc = mfma16(xb, WbX[8 + n][l], acc);
#pragma unroll
      for (int kt = 0; kt < NKH; ++kt) acc = mfma16(hf[kt], WbH[kt][n], acc);
#pragma unroll
      for (int r = 0; r < 4; ++r)
        gsh[l4 * 4 + r][16 * n + lm] = bf16_rne_u16(lecun_tanh_f(acc[r]));
    }
    wave_fence();  // g visible
    bf16x8 gf[4];
#pragma unroll
    for (int kt = 0; kt < 4; ++kt)
      gf[kt] = *(const bf16x8*)&gsh[lm][kt * 32 + l4 * 8];
    // ff1 = g @ W1 + b1; h_new = -A*exp(-(|wt|+|ff1|))*ff1 + A
#pragma unroll
    for (int m = 0; m < NM; ++m) {
      f32x4 fa = {b1v[m], b1v[m], b1v[m], b1v[m]};
#pragma unroll
      for (int kt = 0; kt < 4; ++kt) fa = mfma16(gf[kt], W1f[kt][m], fa);
#pragma unroll
      for (int r = 0; r < 4; ++r) {
        float ff = fa[r];
        float e = __expf(-(wtv[m] + fabsf(ff)));
        float hn = fmaf(-Avv[m] * e, ff, Avv[m]);
        uint16_t hb = bf16_rne_u16(hn);
        zh[l4 * 4 + r][16 * m + lm] = hb;
        if (omask[r]) out[obase[r] + st * o_step_stride + 16 * m] = hb;
      }
    }
    xa = nxa;
    xb = nxb;
  }
}

// ---------- K2: intra FC(64x64) + LN(F,H) + residual(xp f32) -> bf16 ----------
__global__ __launch_bounds__(256) void fc_ln_res_intra(
    const uint16_t* __restrict__ yin, const float* __restrict__ resid,
    const float* __restrict__ W, const float* __restrict__ bias,
    const float* __restrict__ lng, const float* __restrict__ lnb,
    uint16_t* __restrict__ outp) {
  __shared__ float WshT[64][68];
  __shared__ float fcbuf[NF * 65];
  __shared__ float ysh[4][64];
  __shared__ float red[16];
  const int tid = threadIdx.x, n = blockIdx.x;
  for (int e = tid; e < 4096; e += 256) WshT[e & 63][e >> 6] = W[e];
  __syncthreads();
  const int h = tid & 63, rl = tid >> 6;
  const uint16_t* yrow = yin + (size_t)n * GROUP;
  const float bv = bias[h];
  float sum = 0.f, ssq = 0.f;
  for (int r0 = 0; r0 < NF; r0 += 4) {
    int f = r0 + rl;
    __syncthreads();
    ysh[rl][h] = (f < NF) ? bf16u_to_f(yrow[f * 64 + h]) : 0.f;
    __syncthreads();
    if (f < NF) {
      float acc = bv;
#pragma unroll
      for (int k4 = 0; k4 < 64; k4 += 4) {
        float4 wv = *(const float4*)&WshT[h][k4];
        float4 yv = *(const float4*)&ysh[rl][k4];
        acc = fmaf(yv.x, wv.x, acc);
        acc = fmaf(yv.y, wv.y, acc);
        acc = fmaf(yv.z, wv.z, acc);
        acc = fmaf(yv.w, wv.w, acc);
      }
      fcbuf[f * 65 + h] = acc;
      sum += acc;
      ssq += acc * acc;
    }
  }
#pragma unroll
  for (int off = 32; off; off >>= 1) {
    sum += __shfl_xor(sum, off);
    ssq += __shfl_xor(ssq, off);
  }
  const int wave = tid >> 6, lane = tid & 63;
  if (lane == 0) { red[wave] = sum; red[4 + wave] = ssq; }
  __syncthreads();
  if (tid == 0) {
    float s = red[0] + red[1] + red[2] + red[3];
    float q = red[4] + red[5] + red[6] + red[7];
    float mu = s * (1.f / (float)GROUP);
    float var = q * (1.f / (float)GROUP) - mu * mu;
    var = fmaxf(var, 0.f);
    red[8] = mu;
    red[9] = rsqrtf(var + 1e-8f);
  }
  __syncthreads();
  const float mu = red[8], rstd = red[9];
  const float* rrow = resid + (size_t)n * GROUP;
  uint16_t* orow = outp + (size_t)n * GROUP;
  for (int e = tid; e < GROUP; e += 256) {
    int f = e >> 6, hh = e & 63;
    float v = (fcbuf[f * 65 + hh] - mu) * rstd * lng[e] + lnb[e] + rrow[e];
    orow[e] = bf16_rne_u16(v);
  }
}

// ---------- K4: inter FC + LN + residual(bf16) + transpose -> (B,H,T,F) ----------
__global__ __launch_bounds__(256) void fc_ln_res_inter(
    const uint16_t* __restrict__ yin,    // (B*F, T, 64), seq=(b,f)
    const uint16_t* __restrict__ resid,  // (2000,161,64) bf16
    const float* __restrict__ W, const float* __restrict__ bias,
    const float* __restrict__ lng, const float* __restrict__ lnb,
    float* __restrict__ outp) {
  __shared__ float WshT[64][68];
  __shared__ float fcbuf[NF * 65];
  __shared__ float ysh[4][64];
  __shared__ float red[16];
  const int tid = threadIdx.x, n = blockIdx.x;
  const int b = n / 250, t = n - b * 250;
  for (int e = tid; e < 4096; e += 256) WshT[e & 63][e >> 6] = W[e];
  __syncthreads();
  const int h = tid & 63, rl = tid >> 6;
  const float bv = bias[h];
  float sum = 0.f, ssq = 0.f;
  for (int r0 = 0; r0 < NF; r0 += 4) {
    int f = r0 + rl;
    __syncthreads();
    ysh[rl][h] =
        (f < NF) ? bf16u_to_f(yin[((size_t)(b * 161 + f) * 250 + t) * 64 + h])
                 : 0.f;
    __syncthreads();
    if (f < NF) {
      float acc = bv;
#pragma unroll
      for (int k4 = 0; k4 < 64; k4 += 4) {
        float4 wv = *(const float4*)&WshT[h][k4];
        float4 yv = *(const float4*)&ysh[rl][k4];
        acc = fmaf(yv.x, wv.x, acc);
        acc = fmaf(yv.y, wv.y, acc);
        acc = fmaf(yv.z, wv.z, acc);
        acc = fmaf(yv.w, wv.w, acc);
      }
      fcbuf[f * 65 + h] = acc;
      sum += acc;
      ssq += acc * acc;
    }
  }
#pragma unroll
  for (int off = 32; off; off >>= 1) {
    sum += __shfl_xor(sum, off);
    ssq += __shfl_xor(ssq, off);
  }
  const int wave = tid >> 6, lane = tid & 63;
  if (lane == 0) { red[wave] = sum; red[4 + wave] = ssq; }
  __syncthreads();
  if (tid == 0) {
    float s = red[0] + red[1] + red[2] + red[3];
    float q = red[4] + red[5] + red[6] + red[7];
    float mu = s * (1.f / (float)GROUP);
    float var = q * (1.f / (float)GROUP) - mu * mu;
    var = fmaxf(var, 0.f);
    red[8] = mu;
    red[9] = rsqrtf(var + 1e-8f);
  }
  __syncthreads();
  const float mu = red[8], rstd = red[9];
  const uint16_t* rrow = resid + (size_t)n * GROUP;
  for (int e = tid; e < GROUP; e += 256) {
    int f = e >> 6, hh = e & 63;
    fcbuf[f * 65 + hh] = (fcbuf[f * 65 + hh] - mu) * rstd * lng[e] + lnb[e] +
                         bf16u_to_f(rrow[e]);
  }
  __syncthreads();
  float* obase = outp + ((size_t)b * 64 * 250 + t) * NF;  // out[b][h][t][f]
  for (int e = tid; e < GROUP; e += 256) {
    unsigned hh = (unsigned)e / 161u, f = (unsigned)e - hh * 161u;
    obase[(size_t)hh * 250 * NF + f] = fcbuf[f * 65 + hh];
  }
}

// ---------- launcher ----------
extern "C" void kernel_launch(void* const* d_in, const int* in_sizes, int n_in,
                              void* d_out, int out_size, void* d_ws,
                              size_t ws_size, hipStream_t stream) {
  const float* x     = (const float*)d_in[0];
  const float* i1_Wb = (const float*)d_in[1];
  const float* i1_bb = (const float*)d_in[2];
  const float* i1_W1 = (const float*)d_in[3];
  const float* i1_b1 = (const float*)d_in[4];
  const float* i1_wt = (const float*)d_in[5];
  const float* i1_A  = (const float*)d_in[6];
  const float* i2_Wb = (const float*)d_in[7];
  const float* i2_bb = (const float*)d_in[8];
  const float* i2_W1 = (const float*)d_in[9];
  const float* i2_b1 = (const float*)d_in[10];
  const float* i2_wt = (const float*)d_in[11];
  const float* i2_A  = (const float*)d_in[12];
  const float* r_Wb  = (const float*)d_in[13];
  const float* r_bb  = (const float*)d_in[14];
  const float* r_W1  = (const float*)d_in[15];
  const float* r_b1  = (const float*)d_in[16];
  const float* r_wt  = (const float*)d_in[17];
  const float* r_A   = (const float*)d_in[18];
  const float* fcW_i = (const float*)d_in[19];
  const float* fcb_i = (const float*)d_in[20];
  const float* lng_i = (const float*)d_in[21];
  const float* lnb_i = (const float*)d_in[22];
  const float* fcW_r = (const float*)d_in[23];
  const float* fcb_r = (const float*)d_in[24];
  const float* lng_r = (const float*)d_in[25];
  const float* lnb_r = (const float*)d_in[26];

  // ws layout (peak 164,864,000 B — identical to the passing round-1 footprint)
  uint8_t* ws = (uint8_t*)d_ws;
  float*    xp_f    = (float*)ws;                      // 82,432,000 B (dead after K2)
  uint16_t* xp_h    = (uint16_t*)(ws + 82432000);      // 41,216,000 B (dead after K1)
  uint16_t* intra_h = (uint16_t*)(ws + 123648000);     // 41,216,000 B (lives to K4)
  uint16_t* inter_h = (uint16_t*)ws;                   // reuse xp_f region after K2
  uint16_t* ybuf    = (uint16_t*)d_out;                // intra scan out, dead after K2

  // K0: x -> xp (f32 for K2 residual, bf16 for K1 A-frags)
  transpose_kernel<<<dim3(NBT, 6, 2), 256, 0, stream>>>(x, xp_f, xp_h);

  // K1: intra bidirectional scan over F. 2000 seqs/dir, 16/block -> 125/dir.
  mfma_scan_kernel<32><<<250, 64, 0, stream>>>(
      xp_h, ybuf, i1_Wb, i1_bb, i1_W1, i1_b1, i1_wt, i1_A, i2_Wb, i2_bb, i2_W1,
      i2_b1, i2_wt, i2_A, 161, 125, 2000, 2000, 0, GROUP, 64, GROUP, 64, 32);

  // K2: intra FC + LN + residual -> intra_h (bf16)
  fc_ln_res_intra<<<NBT, 256, 0, stream>>>(ybuf, xp_f, fcW_i, fcb_i, lng_i,
                                           lnb_i, intra_h);

  // K3: inter scan over T. 1288 seqs -> 81 blocks (last wave masked).
  mfma_scan_kernel<64><<<81, 64, 0, stream>>>(
      intra_h, inter_h, r_Wb, r_bb, r_W1, r_b1, r_wt, r_A, r_Wb, r_bb, r_W1,
      r_b1, r_wt, r_A, 250, 81, 1288, 161, 250 * GROUP, 64, GROUP, 250 * 64,
      64, 0);

  // K4: inter FC + LN + residual + transpose -> d_out (B,H,T,F) f32
  fc_ln_res_inter<<<NBT, 256, 0, stream>>>(inter_h, intra_h, fcW_r, fcb_r,
                                           lng_r, lnb_r, (float*)d_out);
}

// Round 3
// 933.210 us; speedup vs baseline: 2.2729x; 1.7525x over previous
//
#include <hip/hip_runtime.h>
#include <cstdint>
#include <cstddef>

// B=8, C=64, T=250, F=161, H=64, Hh=32, BB=128
#define BBN 128
#define NBT 2000
#define NF  161
#define GROUP (NF * 64)       // 10304
#define ELEMS 20608000

typedef __attribute__((ext_vector_type(4))) float f32x4;
typedef __attribute__((ext_vector_type(8))) __bf16 bf16x8;
typedef __attribute__((ext_vector_type(8))) uint16_t u16x8;

__device__ __forceinline__ uint16_t bf16_rne_u16(float f) {
  uint32_t u = __float_as_uint(f);
  return (uint16_t)((u + 0x7fffu + ((u >> 16) & 1u)) >> 16);
}
__device__ __forceinline__ float bf16u_to_f(uint16_t h) {
  return __uint_as_float((uint32_t)h << 16);
}
__device__ __forceinline__ float lecun_tanh_f(float x) {
  float e = __expf(1.332f * x);
  return 1.7159f * (1.f - __fdividef(2.f, e + 1.f));
}
__device__ __forceinline__ f32x4 mfma16(bf16x8 a, bf16x8 b, f32x4 c) {
  return __builtin_amdgcn_mfma_f32_16x16x32_bf16(a, b, c, 0, 0, 0);
}
// build a bf16x8 B-fragment from strided f32 weights
__device__ __forceinline__ bf16x8 pack_frag(const float* __restrict__ base, int stride) {
  u16x8 t;
#pragma unroll
  for (int i = 0; i < 8; ++i) t[i] = bf16_rne_u16(base[i * stride]);
  return __builtin_bit_cast(bf16x8, t);
}

// Block barrier that drains only LDS (lgkmcnt), NOT vmcnt — keeps output
// stores and the x-prefetch in flight across the barrier (8-phase pattern).
__device__ __forceinline__ void block_fence() {
  __builtin_amdgcn_sched_barrier(0);
  asm volatile("s_waitcnt lgkmcnt(0)" ::: "memory");
  __builtin_amdgcn_sched_barrier(0);
  __builtin_amdgcn_s_barrier();
  __builtin_amdgcn_sched_barrier(0);
}

// ---------- K0: x (B,C,T,F) -> xp (B*T,F,C) as f32 AND bf16 ----------
__global__ __launch_bounds__(256) void transpose_kernel(
    const float* __restrict__ x, float* __restrict__ xp,
    uint16_t* __restrict__ xph) {
  __shared__ float tile[32][33];
  const int bt = blockIdx.x;
  const int b = bt / 250, t = bt - b * 250;
  const int f0 = blockIdx.y * 32;
  const int c0 = blockIdx.z * 32;
  const int tx = threadIdx.x & 31;
  const int ty4 = (threadIdx.x >> 5) * 4;
  const int f_in = f0 + tx;
#pragma unroll
  for (int i = 0; i < 4; ++i) {
    int c = c0 + ty4 + i;
    if (f_in < NF)
      tile[ty4 + i][tx] = x[((size_t)(b * 64 + c) * 250 + t) * NF + f_in];
  }
  __syncthreads();
  const int c_out = c0 + tx;
#pragma unroll
  for (int i = 0; i < 4; ++i) {
    int f = f0 + ty4 + i;
    if (f < NF) {
      float v = tile[tx][ty4 + i];
      size_t o = ((size_t)bt * NF + f) * 64 + c_out;
      xp[o] = v;
      xph[o] = bf16_rne_u16(v);
    }
  }
}

// ---------- K1/K3: 4-wave cooperative MFMA CfC scan ----------
// 16 sequences per 256-thread block. Wave w owns backbone n-tiles {2w,2w+1}
// and ff1 m-tile w (if w < NM). ALL weight B-frags live in registers.
// Activations (g, h) are stored in LDS in A-FRAGMENT ORDER:
//   frag[kt][lane][i]  at u16 index (kt*64+lane)*8+i
// so phase reads are lane-linear ds_read_b128 (conflict-free baseline).
// A-frag: row=lane&15, k=(lane>>4)*8+i. B-frag: col=lane&15, k=(lane>>4)*8+i.
// C/D: col=lane&15, row=(lane>>4)*4+reg (m89-verified; round-2 passed).
template <int HD>
__global__ __launch_bounds__(256) void mfma_scan4(
    const uint16_t* __restrict__ in, uint16_t* __restrict__ out,
    const float* __restrict__ Wb0, const float* __restrict__ bb0,
    const float* __restrict__ W10, const float* __restrict__ b10,
    const float* __restrict__ wt0, const float* __restrict__ A0,
    const float* __restrict__ Wb1, const float* __restrict__ bb1,
    const float* __restrict__ W11, const float* __restrict__ b11,
    const float* __restrict__ wt1, const float* __restrict__ A1,
    int seq_len, int blocksPerDir, int nseq, int seqs_per_outer,
    int outer_stride, int inner_stride, int step_stride,
    int o_seq_stride, int o_step_stride, int o_col_per_dir) {
  constexpr int NKH = HD / 32;   // h k-tiles (1 or 2)
  constexpr int NKZ = 2 + NKH;   // z k-tiles
  constexpr int NM = HD / 16;    // ff1 m-tiles (2 or 4)
  __shared__ __align__(16) uint16_t gfrag[4 * 64 * 8];    // g A-frags
  __shared__ __align__(16) uint16_t hfrag[NKH * 64 * 8];  // h A-frags

  const int dir = (blockIdx.x >= (unsigned)blocksPerDir) ? 1 : 0;
  const int bid = blockIdx.x - dir * blocksPerDir;
  const float* __restrict__ Wb = dir ? Wb1 : Wb0;
  const float* __restrict__ bb = dir ? bb1 : bb0;
  const float* __restrict__ W1 = dir ? W11 : W10;
  const float* __restrict__ b1 = dir ? b11 : b10;
  const float* __restrict__ wt = dir ? wt1 : wt0;
  const float* __restrict__ Aa = dir ? A1 : A0;
  const bool rev = (dir == 1);
  const int tid = threadIdx.x;
  const int w = tid >> 6, l = tid & 63, l4 = l >> 4, lm = l & 15;
  const bool has_m = (w < NM);

  // ---- one-time weight packing into REGISTERS ----
  bf16x8 WB[2][NKZ];     // backbone B-frags for n-tiles 2w, 2w+1
  float bbv[2];
#pragma unroll
  for (int j = 0; j < 2; ++j) {
    int n = 2 * w + j;
    bbv[j] = bb[16 * n + lm];
#pragma unroll
    for (int kt = 0; kt < NKZ; ++kt)
      WB[j][kt] = pack_frag(&Wb[(kt * 32 + l4 * 8) * BBN + 16 * n + lm], BBN);
  }
  bf16x8 W1f[4];
  float b1v = 0.f, wtv = 0.f, Avv = 0.f;
  if (has_m) {
#pragma unroll
    for (int kt = 0; kt < 4; ++kt)
      W1f[kt] = pack_frag(&W1[(kt * 32 + l4 * 8) * HD + 16 * w + lm], HD);
    b1v = b1[16 * w + lm];
    wtv = fabsf(wt[16 * w + lm]);
    Avv = Aa[16 * w + lm];
  }

  // input base: lane's A-frag sequence = bid*16+lm (clamped for tail block)
  int sA = bid * 16 + lm;
  if (sA > nseq - 1) sA = nseq - 1;
  int ob = sA / seqs_per_outer, oi = sA - ob * seqs_per_outer;
  const uint16_t* inp = in + ob * outer_stride + oi * inner_stride + l4 * 8;
  // output bases (C-layout): seq = bid*16 + l4*4 + r, col = 16w+lm
  int obase[4];
  bool omask[4];
#pragma unroll
  for (int r = 0; r < 4; ++r) {
    int s = bid * 16 + l4 * 4 + r;
    omask[r] = has_m && (s < nseq);
    if (s > nseq - 1) s = nseq - 1;
    obase[r] = s * o_seq_stride + dir * o_col_per_dir + 16 * w + lm;
  }

  // LDS scatter indices (granule*8 + i), granule = kt*64 + dest_lane
  int gi[2];
#pragma unroll
  for (int j = 0; j < 2; ++j)
    gi[j] = (w * 64 + (2 * j + (lm >> 3)) * 16 + l4 * 4) * 8 + (lm & 7);
  const int hi =
      ((w >> 1) * 64 + (2 * (w & 1) + (lm >> 3)) * 16 + l4 * 4) * 8 + (lm & 7);

  for (int e = tid; e < NKH * 64 * 8; e += 256) hfrag[e] = 0;  // h0 = 0
  block_fence();

  bf16x8 xa, xb;
  {
    int f0 = rev ? (seq_len - 1) : 0;
    xa = *(const bf16x8*)(inp + f0 * step_stride);
    xb = *(const bf16x8*)(inp + f0 * step_stride + 32);
  }

  for (int st = 0; st < seq_len; ++st) {
    // ---- phase A: backbone + tanh ----
    bf16x8 hf[NKH];
#pragma unroll
    for (int kt = 0; kt < NKH; ++kt)
      hf[kt] = *(const bf16x8*)&hfrag[(kt * 64 + l) * 8];
    bf16x8 nxa = xa, nxb = xb;
    if (st + 1 < seq_len) {  // prefetch next x (overlaps MFMA+tanh)
      int f = rev ? (seq_len - 2 - st) : (st + 1);
      nxa = *(const bf16x8*)(inp + f * step_stride);
      nxb = *(const bf16x8*)(inp + f * step_stride + 32);
    }
#pragma unroll
    for (int j = 0; j < 2; ++j) {
      f32x4 a0 = {bbv[j], bbv[j], bbv[j], bbv[j]};
      f32x4 a1 = {0.f, 0.f, 0.f, 0.f};
      a0 = mfma16(xa, WB[j][0], a0);
      a1 = mfma16(xb, WB[j][1], a1);
      a0 = mfma16(hf[0], WB[j][2], a0);
      if constexpr (NKH == 2) a1 = mfma16(hf[1], WB[j][3], a1);
      f32x4 acc = a0 + a1;
#pragma unroll
      for (int r = 0; r < 4; ++r)
        gfrag[gi[j] + r * 8] = bf16_rne_u16(lecun_tanh_f(acc[r]));
    }
    block_fence();  // g frags visible; h reads done before h overwrite

    // ---- phase B: ff1 + state update (waves 0..NM-1) ----
    if (has_m) {
      bf16x8 gf[4];
#pragma unroll
      for (int kt = 0; kt < 4; ++kt)
        gf[kt] = *(const bf16x8*)&gfrag[(kt * 64 + l) * 8];
      f32x4 f0 = {b1v, b1v, b1v, b1v};
      f32x4 f1 = {0.f, 0.f, 0.f, 0.f};
      f0 = mfma16(gf[0], W1f[0], f0);
      f1 = mfma16(gf[1], W1f[1], f1);
      f0 = mfma16(gf[2], W1f[2], f0);
      f1 = mfma16(gf[3], W1f[3], f1);
      f32x4 fa = f0 + f1;
#pragma unroll
      for (int r = 0; r < 4; ++r) {
        float ff = fa[r];
        float e = __expf(-(wtv + fabsf(ff)));
        float hn = fmaf(-Avv * e, ff, Avv);
        uint16_t hb = bf16_rne_u16(hn);
        hfrag[hi + r * 8] = hb;
        if (omask[r]) out[obase[r] + st * o_step_stride] = hb;
      }
    }
    block_fence();  // h frags visible for next step; gfrag WAR protection
    xa = nxa;
    xb = nxb;
  }
}

// ---------- K2: intra FC(64x64) + LN(F,H) + residual(xp f32) -> bf16 ----------
__global__ __launch_bounds__(256) void fc_ln_res_intra(
    const uint16_t* __restrict__ yin, const float* __restrict__ resid,
    const float* __restrict__ W, const float* __restrict__ bias,
    const float* __restrict__ lng, const float* __restrict__ lnb,
    uint16_t* __restrict__ outp) {
  __shared__ float WshT[64][68];
  __shared__ float fcbuf[NF * 65];
  __shared__ float ysh[4][64];
  __shared__ float red[16];
  const int tid = threadIdx.x, n = blockIdx.x;
  for (int e = tid; e < 4096; e += 256) WshT[e & 63][e >> 6] = W[e];
  __syncthreads();
  const int h = tid & 63, rl = tid >> 6;
  const uint16_t* yrow = yin + (size_t)n * GROUP;
  const float bv = bias[h];
  float sum = 0.f, ssq = 0.f;
  for (int r0 = 0; r0 < NF; r0 += 4) {
    int f = r0 + rl;
    __syncthreads();
    ysh[rl][h] = (f < NF) ? bf16u_to_f(yrow[f * 64 + h]) : 0.f;
    __syncthreads();
    if (f < NF) {
      float acc = bv;
#pragma unroll
      for (int k4 = 0; k4 < 64; k4 += 4) {
        float4 wv = *(const float4*)&WshT[h][k4];
        float4 yv = *(const float4*)&ysh[rl][k4];
        acc = fmaf(yv.x, wv.x, acc);
        acc = fmaf(yv.y, wv.y, acc);
        acc = fmaf(yv.z, wv.z, acc);
        acc = fmaf(yv.w, wv.w, acc);
      }
      fcbuf[f * 65 + h] = acc;
      sum += acc;
      ssq += acc * acc;
    }
  }
#pragma unroll
  for (int off = 32; off; off >>= 1) {
    sum += __shfl_xor(sum, off);
    ssq += __shfl_xor(ssq, off);
  }
  const int wave = tid >> 6, lane = tid & 63;
  if (lane == 0) { red[wave] = sum; red[4 + wave] = ssq; }
  __syncthreads();
  if (tid == 0) {
    float s = red[0] + red[1] + red[2] + red[3];
    float q = red[4] + red[5] + red[6] + red[7];
    float mu = s * (1.f / (float)GROUP);
    float var = q * (1.f / (float)GROUP) - mu * mu;
    var = fmaxf(var, 0.f);
    red[8] = mu;
    red[9] = rsqrtf(var + 1e-8f);
  }
  __syncthreads();
  const float mu = red[8], rstd = red[9];
  const float* rrow = resid + (size_t)n * GROUP;
  uint16_t* orow = outp + (size_t)n * GROUP;
  for (int e = tid; e < GROUP; e += 256) {
    int f = e >> 6, hh = e & 63;
    float v = (fcbuf[f * 65 + hh] - mu) * rstd * lng[e] + lnb[e] + rrow[e];
    orow[e] = bf16_rne_u16(v);
  }
}

// ---------- K4: inter FC + LN + residual(bf16) + transpose -> (B,H,T,F) ----------
__global__ __launch_bounds__(256) void fc_ln_res_inter(
    const uint16_t* __restrict__ yin,    // (B*F, T, 64), seq=(b,f)
    const uint16_t* __restrict__ resid,  // (2000,161,64) bf16
    const float* __restrict__ W, const float* __restrict__ bias,
    const float* __restrict__ lng, const float* __restrict__ lnb,
    float* __restrict__ outp) {
  __shared__ float WshT[64][68];
  __shared__ float fcbuf[NF * 65];
  __shared__ float ysh[4][64];
  __shared__ float red[16];
  const int tid = threadIdx.x, n = blockIdx.x;
  const int b = n / 250, t = n - b * 250;
  for (int e = tid; e < 4096; e += 256) WshT[e & 63][e >> 6] = W[e];
  __syncthreads();
  const int h = tid & 63, rl = tid >> 6;
  const float bv = bias[h];
  float sum = 0.f, ssq = 0.f;
  for (int r0 = 0; r0 < NF; r0 += 4) {
    int f = r0 + rl;
    __syncthreads();
    ysh[rl][h] =
        (f < NF) ? bf16u_to_f(yin[((size_t)(b * 161 + f) * 250 + t) * 64 + h])
                 : 0.f;
    __syncthreads();
    if (f < NF) {
      float acc = bv;
#pragma unroll
      for (int k4 = 0; k4 < 64; k4 += 4) {
        float4 wv = *(const float4*)&WshT[h][k4];
        float4 yv = *(const float4*)&ysh[rl][k4];
        acc = fmaf(yv.x, wv.x, acc);
        acc = fmaf(yv.y, wv.y, acc);
        acc = fmaf(yv.z, wv.z, acc);
        acc = fmaf(yv.w, wv.w, acc);
      }
      fcbuf[f * 65 + h] = acc;
      sum += acc;
      ssq += acc * acc;
    }
  }
#pragma unroll
  for (int off = 32; off; off >>= 1) {
    sum += __shfl_xor(sum, off);
    ssq += __shfl_xor(ssq, off);
  }
  const int wave = tid >> 6, lane = tid & 63;
  if (lane == 0) { red[wave] = sum; red[4 + wave] = ssq; }
  __syncthreads();
  if (tid == 0) {
    float s = red[0] + red[1] + red[2] + red[3];
    float q = red[4] + red[5] + red[6] + red[7];
    float mu = s * (1.f / (float)GROUP);
    float var = q * (1.f / (float)GROUP) - mu * mu;
    var = fmaxf(var, 0.f);
    red[8] = mu;
    red[9] = rsqrtf(var + 1e-8f);
  }
  __syncthreads();
  const float mu = red[8], rstd = red[9];
  const uint16_t* rrow = resid + (size_t)n * GROUP;
  for (int e = tid; e < GROUP; e += 256) {
    int f = e >> 6, hh = e & 63;
    fcbuf[f * 65 + hh] = (fcbuf[f * 65 + hh] - mu) * rstd * lng[e] + lnb[e] +
                         bf16u_to_f(rrow[e]);
  }
  __syncthreads();
  float* obase = outp + ((size_t)b * 64 * 250 + t) * NF;  // out[b][h][t][f]
  for (int e = tid; e < GROUP; e += 256) {
    unsigned hh = (unsigned)e / 161u, f = (unsigned)e - hh * 161u;
    obase[(size_t)hh * 250 * NF + f] = fcbuf[f * 65 + hh];
  }
}

// ---------- launcher ----------
extern "C" void kernel_launch(void* const* d_in, const int* in_sizes, int n_in,
                              void* d_out, int out_size, void* d_ws,
                              size_t ws_size, hipStream_t stream) {
  const float* x     = (const float*)d_in[0];
  const float* i1_Wb = (const float*)d_in[1];
  const float* i1_bb = (const float*)d_in[2];
  const float* i1_W1 = (const float*)d_in[3];
  const float* i1_b1 = (const float*)d_in[4];
  const float* i1_wt = (const float*)d_in[5];
  const float* i1_A  = (const float*)d_in[6];
  const float* i2_Wb = (const float*)d_in[7];
  const float* i2_bb = (const float*)d_in[8];
  const float* i2_W1 = (const float*)d_in[9];
  const float* i2_b1 = (const float*)d_in[10];
  const float* i2_wt = (const float*)d_in[11];
  const float* i2_A  = (const float*)d_in[12];
  const float* r_Wb  = (const float*)d_in[13];
  const float* r_bb  = (const float*)d_in[14];
  const float* r_W1  = (const float*)d_in[15];
  const float* r_b1  = (const float*)d_in[16];
  const float* r_wt  = (const float*)d_in[17];
  const float* r_A   = (const float*)d_in[18];
  const float* fcW_i = (const float*)d_in[19];
  const float* fcb_i = (const float*)d_in[20];
  const float* lng_i = (const float*)d_in[21];
  const float* lnb_i = (const float*)d_in[22];
  const float* fcW_r = (const float*)d_in[23];
  const float* fcb_r = (const float*)d_in[24];
  const float* lng_r = (const float*)d_in[25];
  const float* lnb_r = (const float*)d_in[26];

  // ws layout (peak 164,864,000 B — proven footprint)
  uint8_t* ws = (uint8_t*)d_ws;
  float*    xp_f    = (float*)ws;                      // dead after K2
  uint16_t* xp_h    = (uint16_t*)(ws + 82432000);      // dead after K1
  uint16_t* intra_h = (uint16_t*)(ws + 123648000);     // lives to K4
  uint16_t* inter_h = (uint16_t*)ws;                   // reuse xp_f after K2
  uint16_t* ybuf    = (uint16_t*)d_out;                // dead after K2

  // K0: x -> xp (f32 for K2 residual, bf16 for K1 A-frags)
  transpose_kernel<<<dim3(NBT, 6, 2), 256, 0, stream>>>(x, xp_f, xp_h);

  // K1: intra bidirectional scan over F. 2000 seqs/dir, 16/block -> 125/dir.
  mfma_scan4<32><<<250, 256, 0, stream>>>(
      xp_h, ybuf, i1_Wb, i1_bb, i1_W1, i1_b1, i1_wt, i1_A, i2_Wb, i2_bb, i2_W1,
      i2_b1, i2_wt, i2_A, 161, 125, 2000, 2000, 0, GROUP, 64, GROUP, 64, 32);

  // K2: intra FC + LN + residual -> intra_h (bf16)
  fc_ln_res_intra<<<NBT, 256, 0, stream>>>(ybuf, xp_f, fcW_i, fcb_i, lng_i,
                                           lnb_i, intra_h);

  // K3: inter scan over T. 1288 seqs -> 81 blocks (tail masked).
  mfma_scan4<64><<<81, 256, 0, stream>>>(
      intra_h, inter_h, r_Wb, r_bb, r_W1, r_b1, r_wt, r_A, r_Wb, r_bb, r_W1,
      r_b1, r_wt, r_A, 250, 81, 1288, 161, 250 * GROUP, 64, GROUP, 250 * 64,
      64, 0);

  // K4: inter FC + LN + residual + transpose -> d_out (B,H,T,F) f32
  fc_ln_res_inter<<<NBT, 256, 0, stream>>>(inter_h, intra_h, fcW_r, fcb_r,
                                           lng_r, lnb_r, (float*)d_out);
}

// Round 6
// 617.875 us; speedup vs baseline: 3.4329x; 1.5104x over previous
//
#include <hip/hip_runtime.h>
#include <cstdint>
#include <cstddef>

// B=8, C=64, T=250, F=161, H=64, Hh=32, BB=128
#define BBN 128
#define NBT 2000
#define NF  161
#define GROUP (NF * 64)       // 10304

typedef __attribute__((ext_vector_type(4))) float f32x4;
typedef __attribute__((ext_vector_type(8))) __bf16 bf16x8;
typedef __attribute__((ext_vector_type(8))) uint16_t u16x8;

__device__ __forceinline__ uint16_t bf16_rne_u16(float f) {
  uint32_t u = __float_as_uint(f);
  return (uint16_t)((u + 0x7fffu + ((u >> 16) & 1u)) >> 16);
}
__device__ __forceinline__ float bf16u_to_f(uint16_t h) {
  return __uint_as_float((uint32_t)h << 16);
}
__device__ __forceinline__ float lecun_tanh_f(float x) {
  float e = __expf(1.332f * x);
  return 1.7159f * (1.f - __fdividef(2.f, e + 1.f));
}
__device__ __forceinline__ f32x4 mfma16(bf16x8 a, bf16x8 b, f32x4 c) {
  return __builtin_amdgcn_mfma_f32_16x16x32_bf16(a, b, c, 0, 0, 0);
}
__device__ __forceinline__ bf16x8 pack_frag(const float* __restrict__ base, int stride) {
  u16x8 t;
#pragma unroll
  for (int i = 0; i < 8; ++i) t[i] = bf16_rne_u16(base[i * stride]);
  return __builtin_bit_cast(bf16x8, t);
}

// Block barrier draining only LDS (lgkmcnt), NOT vmcnt — output stores and
// the x-prefetch stay in flight across the barrier.
__device__ __forceinline__ void block_fence() {
  __builtin_amdgcn_sched_barrier(0);
  asm volatile("s_waitcnt lgkmcnt(0)" ::: "memory");
  __builtin_amdgcn_sched_barrier(0);
  __builtin_amdgcn_s_barrier();
  __builtin_amdgcn_sched_barrier(0);
}

// ---------- K0: x (B,C,T,F) -> xp_h (B*T,F,C) bf16 ----------
__global__ __launch_bounds__(256) void transpose_kernel(
    const float* __restrict__ x, uint16_t* __restrict__ xph) {
  __shared__ float tile[32][33];
  const int bt = blockIdx.x;
  const int b = bt / 250, t = bt - b * 250;
  const int f0 = blockIdx.y * 32;
  const int c0 = blockIdx.z * 32;
  const int tx = threadIdx.x & 31;
  const int ty4 = (threadIdx.x >> 5) * 4;
  const int f_in = f0 + tx;
#pragma unroll
  for (int i = 0; i < 4; ++i) {
    int c = c0 + ty4 + i;
    if (f_in < NF)
      tile[ty4 + i][tx] = x[((size_t)(b * 64 + c) * 250 + t) * NF + f_in];
  }
  __syncthreads();
  const int c_out = c0 + tx;
#pragma unroll
  for (int i = 0; i < 4; ++i) {
    int f = f0 + ty4 + i;
    if (f < NF) {
      size_t o = ((size_t)bt * NF + f) * 64 + c_out;
      xph[o] = bf16_rne_u16(tile[tx][ty4 + i]);
    }
  }
}

// ---------- K1/K3: 8-wave cooperative MFMA CfC scan ----------
// 16 sequences per 512-thread block. Wave w owns backbone n-tile w; waves
// 0..NM-1 own ff1 m-tile w. Weights in registers. Activations (g, h) cross
// phases through LDS in A-FRAGMENT ORDER (round-3 verified mapping):
//   dest u16 index = ((c>>5)*64 + ((c&31)>>3)*16 + row)*8 + (c&7)
// which for col c = 16w+lm, row = l4*4+r reduces to gi below (gi == hi).
template <int HD>
__global__ __launch_bounds__(512) void mfma_scan8(
    const uint16_t* __restrict__ in, uint16_t* __restrict__ out,
    const float* __restrict__ Wb0, const float* __restrict__ bb0,
    const float* __restrict__ W10, const float* __restrict__ b10,
    const float* __restrict__ wt0, const float* __restrict__ A0,
    const float* __restrict__ Wb1, const float* __restrict__ bb1,
    const float* __restrict__ W11, const float* __restrict__ b11,
    const float* __restrict__ wt1, const float* __restrict__ A1,
    int seq_len, int blocksPerDir, int nseq, int seqs_per_outer,
    int outer_stride, int inner_stride, int step_stride,
    int o_seq_stride, int o_step_stride, int o_col_per_dir) {
  constexpr int NKH = HD / 32;   // h k-tiles (1 or 2)
  constexpr int NKZ = 2 + NKH;   // z k-tiles
  constexpr int NM = HD / 16;    // ff1 m-tiles (2 or 4)
  __shared__ __align__(16) uint16_t gfrag[4 * 64 * 8];    // g A-frags
  __shared__ __align__(16) uint16_t hfrag[NKH * 64 * 8];  // h A-frags

  const int dir = (blockIdx.x >= (unsigned)blocksPerDir) ? 1 : 0;
  const int bid = blockIdx.x - dir * blocksPerDir;
  const float* __restrict__ Wb = dir ? Wb1 : Wb0;
  const float* __restrict__ bb = dir ? bb1 : bb0;
  const float* __restrict__ W1 = dir ? W11 : W10;
  const float* __restrict__ b1 = dir ? b11 : b10;
  const float* __restrict__ wt = dir ? wt1 : wt0;
  const float* __restrict__ Aa = dir ? A1 : A0;
  const bool rev = (dir == 1);
  const int tid = threadIdx.x;
  const int w = tid >> 6, l = tid & 63, l4 = l >> 4, lm = l & 15;
  const bool has_m = (w < NM);

  // ---- weights in registers ----
  bf16x8 WB[NKZ];
  const float bbv = bb[16 * w + lm];
#pragma unroll
  for (int kt = 0; kt < NKZ; ++kt)
    WB[kt] = pack_frag(&Wb[(kt * 32 + l4 * 8) * BBN + 16 * w + lm], BBN);
  bf16x8 W1f[4];
  float b1v = 0.f, wtv = 0.f, Avv = 0.f;
  if (has_m) {
#pragma unroll
    for (int kt = 0; kt < 4; ++kt)
      W1f[kt] = pack_frag(&W1[(kt * 32 + l4 * 8) * HD + 16 * w + lm], HD);
    b1v = b1[16 * w + lm];
    wtv = fabsf(wt[16 * w + lm]);
    Avv = Aa[16 * w + lm];
  }

  // input base: A-frag row = sequence bid*16+lm (clamped for tail block)
  int sA = bid * 16 + lm;
  if (sA > nseq - 1) sA = nseq - 1;
  int ob = sA / seqs_per_outer, oi = sA - ob * seqs_per_outer;
  const uint16_t* inp =
      in + (size_t)ob * outer_stride + (size_t)oi * inner_stride + l4 * 8;
  // output bases (C-layout): seq = bid*16 + l4*4 + r, col = 16w+lm
  int obase[4];
  bool omask[4];
#pragma unroll
  for (int r = 0; r < 4; ++r) {
    int s = bid * 16 + l4 * 4 + r;
    omask[r] = has_m && (s < nseq);
    if (s > nseq - 1) s = nseq - 1;
    obase[r] = s * o_seq_stride + dir * o_col_per_dir + 16 * w + lm;
  }

  const int gi =
      ((w >> 1) * 64 + (2 * (w & 1) + (lm >> 3)) * 16 + l4 * 4) * 8 + (lm & 7);

  for (int e = tid; e < NKH * 64 * 8; e += 512) hfrag[e] = 0;  // h0 = 0
  block_fence();

  bf16x8 xa, xb;
  {
    int f0 = rev ? (seq_len - 1) : 0;
    xa = *(const bf16x8*)(inp + (size_t)f0 * step_stride);
    xb = *(const bf16x8*)(inp + (size_t)f0 * step_stride + 32);
  }

  for (int st = 0; st < seq_len; ++st) {
    // ---- phase A: backbone n-tile w + tanh ----
    bf16x8 hf[NKH];
#pragma unroll
    for (int kt = 0; kt < NKH; ++kt)
      hf[kt] = *(const bf16x8*)&hfrag[(kt * 64 + l) * 8];
    bf16x8 nxa = xa, nxb = xb;
    if (st + 1 < seq_len) {  // prefetch next x (overlaps MFMA+tanh)
      int f = rev ? (seq_len - 2 - st) : (st + 1);
      nxa = *(const bf16x8*)(inp + (size_t)f * step_stride);
      nxb = *(const bf16x8*)(inp + (size_t)f * step_stride + 32);
    }
    f32x4 a0 = {bbv, bbv, bbv, bbv};
    f32x4 a1 = {0.f, 0.f, 0.f, 0.f};
    a0 = mfma16(xa, WB[0], a0);
    a1 = mfma16(xb, WB[1], a1);
    a0 = mfma16(hf[0], WB[2], a0);
    if constexpr (NKH == 2) a1 = mfma16(hf[1], WB[3], a1);
    f32x4 acc = a0 + a1;
#pragma unroll
    for (int r = 0; r < 4; ++r)
      gfrag[gi + r * 8] = bf16_rne_u16(lecun_tanh_f(acc[r]));
    block_fence();  // g visible; h reads done before h overwrite

    // ---- phase B: ff1 m-tile w + state update (waves 0..NM-1) ----
    if (has_m) {
      bf16x8 gf[4];
#pragma unroll
      for (int kt = 0; kt < 4; ++kt)
        gf[kt] = *(const bf16x8*)&gfrag[(kt * 64 + l) * 8];
      f32x4 f0 = {b1v, b1v, b1v, b1v};
      f32x4 f1 = {0.f, 0.f, 0.f, 0.f};
      f0 = mfma16(gf[0], W1f[0], f0);
      f1 = mfma16(gf[1], W1f[1], f1);
      f0 = mfma16(gf[2], W1f[2], f0);
      f1 = mfma16(gf[3], W1f[3], f1);
      f32x4 fa = f0 + f1;
#pragma unroll
      for (int r = 0; r < 4; ++r) {
        float ff = fa[r];
        float e = __expf(-(wtv + fabsf(ff)));
        float hn = fmaf(-Avv * e, ff, Avv);
        uint16_t hb = bf16_rne_u16(hn);
        hfrag[gi + r * 8] = hb;  // same mapping as g (col=16w+lm)
        if (omask[r]) out[obase[r] + st * o_step_stride] = hb;
      }
    }
    block_fence();  // h visible for next step; gfrag WAR protection
    xa = nxa;
    xb = nxb;
  }
}

// ---------- K2/K4: MFMA FC(64x64) + LN(F,H) + residual ----------
// One (b,t) group per 256-thread block. y staged in LDS as A-tiles
// ([176 rows][72 u16] — 16B-aligned rows, 2-way banks = free). W B-frags in
// registers (wave w -> n-tile w). LN stats from C-frags (row<161 masked),
// normalized pre-affine values scattered back to ysh (bf16), then a fully
// coalesced affine+residual pass. TRANS: extra LDS transpose (pad 73,
// conflict-free) and f32 store to (B,H,T,F).
template <bool TRANS>
__global__ __launch_bounds__(256) void fc_ln_mfma(
    const uint16_t* __restrict__ yin, const uint16_t* __restrict__ resid,
    const float* __restrict__ W, const float* __restrict__ bias,
    const float* __restrict__ lng, const float* __restrict__ lnb,
    void* __restrict__ outp) {
  __shared__ __align__(16) uint16_t ysh[176 * 72];
  __shared__ float red[16];
  __shared__ float fsh[TRANS ? NF * 73 : 4];

  const int tid = threadIdx.x, n = blockIdx.x;
  const int w = tid >> 6, l = tid & 63, l4 = l >> 4, lm = l & 15;
  const int b = n / 250, t = n - b * 250;

  // stage y -> ysh (rows >=161 zeroed)
  const size_t ybase = TRANS ? ((size_t)b * 40250 + t) * 64 : (size_t)n * GROUP;
  const int rstride = TRANS ? 16000 : 64;
  for (int idx = tid; idx < 176 * 8; idx += 256) {
    int f = idx >> 3, k8 = (idx & 7) * 8;
    uint64_t lo = 0, hi = 0;
    if (f < NF) {
      const uint64_t* p =
          (const uint64_t*)(yin + ybase + (size_t)f * rstride + k8);
      lo = p[0];
      hi = p[1];
    }
    uint64_t* q = (uint64_t*)&ysh[f * 72 + k8];
    q[0] = lo;
    q[1] = hi;
  }

  bf16x8 Wf[2];
#pragma unroll
  for (int kt = 0; kt < 2; ++kt)
    Wf[kt] = pack_frag(&W[(kt * 32 + l4 * 8) * 64 + 16 * w + lm], 64);
  const float bv = bias[16 * w + lm];
  __syncthreads();

  // FC: 11 m-tiles x 2 k-tiles per wave
  f32x4 acc[11];
#pragma unroll
  for (int m = 0; m < 11; ++m) {
    bf16x8 a0 = *(const bf16x8*)&ysh[(m * 16 + lm) * 72 + l4 * 8];
    bf16x8 a1 = *(const bf16x8*)&ysh[(m * 16 + lm) * 72 + 32 + l4 * 8];
    f32x4 c = {bv, bv, bv, bv};
    c = mfma16(a0, Wf[0], c);
    c = mfma16(a1, Wf[1], c);
    acc[m] = c;
  }

  // LN stats (rows >= 161 excluded; m=10 contributes only row 160 = l4==0,r==0)
  float sum = 0.f, ssq = 0.f;
#pragma unroll
  for (int m = 0; m < 10; ++m)
#pragma unroll
    for (int r = 0; r < 4; ++r) {
      float v = acc[m][r];
      sum += v;
      ssq += v * v;
    }
  if (l4 == 0) {
    float v = acc[10][0];
    sum += v;
    ssq += v * v;
  }
#pragma unroll
  for (int off = 32; off; off >>= 1) {
    sum += __shfl_xor(sum, off);
    ssq += __shfl_xor(ssq, off);
  }
  if (l == 0) {
    red[w] = sum;
    red[4 + w] = ssq;
  }
  __syncthreads();  // also guarantees all A-frag reads done (lgkm drained)
  if (tid == 0) {
    float s = red[0] + red[1] + red[2] + red[3];
    float q = red[4] + red[5] + red[6] + red[7];
    float mu = s * (1.f / (float)GROUP);
    float var = q * (1.f / (float)GROUP) - mu * mu;
    red[8] = mu;
    red[9] = rsqrtf(fmaxf(var, 0.f) + 1e-8f);
  }
  __syncthreads();
  const float mu = red[8], rstd = red[9];

  // scatter normalized (pre-affine) back into ysh as bf16
#pragma unroll
  for (int m = 0; m < 11; ++m)
#pragma unroll
    for (int r = 0; r < 4; ++r) {
      int row = m * 16 + l4 * 4 + r;
      if (row < NF)
        ysh[row * 72 + 16 * w + lm] = bf16_rne_u16((acc[m][r] - mu) * rstd);
    }
  __syncthreads();

  // coalesced affine + residual
  const uint16_t* rrow = resid + (size_t)n * GROUP;
  if (!TRANS) {
    uint16_t* orow = (uint16_t*)outp + (size_t)n * GROUP;
    for (int idx = tid; idx < GROUP; idx += 256) {
      int f = idx >> 6, h = idx & 63;
      float v = bf16u_to_f(ysh[f * 72 + h]) * lng[idx] + lnb[idx] +
                bf16u_to_f(rrow[idx]);
      orow[idx] = bf16_rne_u16(v);
    }
  } else {
    for (int idx = tid; idx < GROUP; idx += 256) {
      int f = idx >> 6, h = idx & 63;
      fsh[f * 73 + h] = bf16u_to_f(ysh[f * 72 + h]) * lng[idx] + lnb[idx] +
                        bf16u_to_f(rrow[idx]);
    }
    __syncthreads();
    float* ob2 = (float*)outp + (size_t)b * 2576000 + (size_t)t * 161;
    for (int idx = tid; idx < GROUP; idx += 256) {
      unsigned h = (unsigned)idx / 161u, f = (unsigned)idx - h * 161u;
      ob2[(size_t)h * 40250 + f] = fsh[f * 73 + h];
    }
  }
}

// ---------- launcher ----------
extern "C" void kernel_launch(void* const* d_in, const int* in_sizes, int n_in,
                              void* d_out, int out_size, void* d_ws,
                              size_t ws_size, hipStream_t stream) {
  const float* x     = (const float*)d_in[0];
  const float* i1_Wb = (const float*)d_in[1];
  const float* i1_bb = (const float*)d_in[2];
  const float* i1_W1 = (const float*)d_in[3];
  const float* i1_b1 = (const float*)d_in[4];
  const float* i1_wt = (const float*)d_in[5];
  const float* i1_A  = (const float*)d_in[6];
  const float* i2_Wb = (const float*)d_in[7];
  const float* i2_bb = (const float*)d_in[8];
  const float* i2_W1 = (const float*)d_in[9];
  const float* i2_b1 = (const float*)d_in[10];
  const float* i2_wt = (const float*)d_in[11];
  const float* i2_A  = (const float*)d_in[12];
  const float* r_Wb  = (const float*)d_in[13];
  const float* r_bb  = (const float*)d_in[14];
  const float* r_W1  = (const float*)d_in[15];
  const float* r_b1  = (const float*)d_in[16];
  const float* r_wt  = (const float*)d_in[17];
  const float* r_A   = (const float*)d_in[18];
  const float* fcW_i = (const float*)d_in[19];
  const float* fcb_i = (const float*)d_in[20];
  const float* lng_i = (const float*)d_in[21];
  const float* lnb_i = (const float*)d_in[22];
  const float* fcW_r = (const float*)d_in[23];
  const float* fcb_r = (const float*)d_in[24];
  const float* lng_r = (const float*)d_in[25];
  const float* lnb_r = (const float*)d_in[26];

  // ws layout: 3 x 41,216,000 B = 123.6 MB (< proven 164.8 MB)
  uint8_t* ws = (uint8_t*)d_ws;
  uint16_t* xp_h    = (uint16_t*)ws;                   // dead after K2
  uint16_t* intra_h = (uint16_t*)(ws + 41216000);      // lives to K4
  uint16_t* inter_h = (uint16_t*)(ws + 82432000);      // K3 out, K4 in
  uint16_t* ybuf    = (uint16_t*)d_out;                // dead after K2

  // K0: x -> xp_h (bf16)
  transpose_kernel<<<dim3(NBT, 6, 2), 256, 0, stream>>>(x, xp_h);

  // K1: intra bidirectional scan over F. 2000 seqs/dir, 16/block -> 125/dir.
  mfma_scan8<32><<<250, 512, 0, stream>>>(
      xp_h, ybuf, i1_Wb, i1_bb, i1_W1, i1_b1, i1_wt, i1_A, i2_Wb, i2_bb, i2_W1,
      i2_b1, i2_wt, i2_A, 161, 125, 2000, 2000, 0, GROUP, 64, GROUP, 64, 32);

  // K2: intra FC + LN + residual(xp_h) -> intra_h (bf16)
  fc_ln_mfma<false><<<NBT, 256, 0, stream>>>(ybuf, xp_h, fcW_i, fcb_i, lng_i,
                                             lnb_i, intra_h);

  // K3: inter scan over T. 1288 seqs -> 81 blocks (tail masked).
  mfma_scan8<64><<<81, 512, 0, stream>>>(
      intra_h, inter_h, r_Wb, r_bb, r_W1, r_b1, r_wt, r_A, r_Wb, r_bb, r_W1,
      r_b1, r_wt, r_A, 250, 81, 1288, 161, 250 * GROUP, 64, GROUP, 16000, 64,
      0);

  // K4: inter FC + LN + residual(intra_h) + transpose -> d_out (B,H,T,F) f32
  fc_ln_mfma<true><<<NBT, 256, 0, stream>>>(inter_h, intra_h, fcW_r, fcb_r,
                                            lng_r, lnb_r, d_out);
}